// Round 10
// baseline (456.084 us; speedup 1.0000x reference)
//
#include <hip/hip_runtime.h>
#include <hip/hip_fp16.h>

#define NN 100000
#define NE 1600000
#define DD 32
#define NL 3
#define NK 3
#define NB ((NN + 255) / 256)   // 391 scan blocks
#define NTB (NN / 16)           // 6250 fused-kernel blocks

typedef _Float16 half8 __attribute__((ext_vector_type(8)));
typedef float f32x4 __attribute__((ext_vector_type(4)));

// --- packed histogram: count [48..], fp(2^-40) wsum [0..48).
//     Returned old count = this edge's rank within its target's list. ---
__global__ void hist_rank_kernel(const int* __restrict__ col, const float* __restrict__ w,
                                 unsigned long long* __restrict__ pk, int* __restrict__ rank) {
    int e = blockIdx.x * blockDim.x + threadIdx.x;
    if (e < NE) {
        int c = __builtin_nontemporal_load(col + e);
        float we = __builtin_nontemporal_load(w + e);
        unsigned long long enc = (1ull << 48) |
            (unsigned long long)((double)we * 1099511627776.0);  // w * 2^40
        unsigned long long old = atomicAdd(&pk[c], enc);
        rank[e] = (int)(old >> 48);
    }
}

// --- per-block scan of counts (from pk) -> ptr partial + bsum; also dis ---
__global__ void scan_block_kernel(const unsigned long long* __restrict__ pk,
                                  float* __restrict__ dis,
                                  int* __restrict__ ptr, int* __restrict__ bsum) {
    __shared__ int s[256];
    int t = threadIdx.x;
    int i = blockIdx.x * 256 + t;
    unsigned long long p = (i < NN) ? pk[i] : 0ull;
    int v = (int)(p >> 48);
    s[t] = v;
    __syncthreads();
    for (int off = 1; off < 256; off <<= 1) {
        int add = (t >= off) ? s[t - off] : 0;
        __syncthreads();
        s[t] += add;
        __syncthreads();
    }
    if (i < NN) {
        ptr[i] = s[t] - v;
        float deg = (float)((double)(p & 0xFFFFFFFFFFFFull) * (1.0 / 1099511627776.0));
        dis[i] = deg > 0.f ? rsqrtf(deg) : 0.f;
    }
    if (t == 255) bsum[blockIdx.x] = s[255];
}

// --- fused top-scan + add: each block reduces bsum[j<b] itself; emit pc=(ptr,dis) ---
__global__ void scan_add_kernel(int* __restrict__ ptr, const int* __restrict__ bsum,
                                const float* __restrict__ dis, int2* __restrict__ pc) {
    __shared__ int red[256];
    int b = blockIdx.x, t = threadIdx.x;
    int acc = 0;
    for (int j = t; j < NB; j += 256)
        if (j < b) acc += bsum[j];
    red[t] = acc;
    __syncthreads();
    for (int off = 128; off > 0; off >>= 1) {
        if (t < off) red[t] += red[t + off];
        __syncthreads();
    }
    int ex = red[0];
    int i = b * 256 + t;
    if (i < NN) {
        int pf = ptr[i] + ex;
        ptr[i] = pf;
        pc[i] = make_int2(pf, __float_as_int(dis[i]));
    }
    if (b == 0 && t == 0) ptr[NN] = NE;
}

// --- fill CSR (no atomics): epair = (fp16_bits(norm) << 17) | src ---
__global__ void fill_kernel(const int* __restrict__ row, const int* __restrict__ col,
                            const float* __restrict__ w, const int* __restrict__ rank,
                            const float* __restrict__ dis, const int2* __restrict__ pc,
                            unsigned* __restrict__ epair) {
    int e = blockIdx.x * blockDim.x + threadIdx.x;
    if (e < NE) {
        int r = __builtin_nontemporal_load(row + e);
        int c = __builtin_nontemporal_load(col + e);
        float we = __builtin_nontemporal_load(w + e);
        int rk = __builtin_nontemporal_load(rank + e);
        int2 P = pc[c];
        float nv = dis[r] * we * __int_as_float(P.y);
        unsigned hb = (unsigned)__half_as_ushort(__float2half(nv));
        epair[P.x + rk] = (hb << 17) | (unsigned)r;
    }
}

// --- combined: blocks 0..NL-1 pre-pack B fragments; the rest convert x -> fp16 ---
__global__ void cvtprep_kernel(const float* __restrict__ x, __half* __restrict__ xh,
                               const float* __restrict__ W, half8* __restrict__ Bpk) {
    int bx = blockIdx.x;
    int t = threadIdx.x;
    if (bx < NL) {
        if (t < 64) {
            int l = bx;
            int m = t & 15, kq = t >> 4;
            for (int c = 0; c < 4; ++c) {
                for (int h = 0; h < 2; ++h) {
                    half8 hi, lo;
                    for (int j = 0; j < 8; ++j) {
                        float wv = W[(size_t)((l * 4 + c) * DD + kq * 8 + j) * DD + h * 16 + m];
                        _Float16 wh = (_Float16)wv;
                        hi[j] = wh;
                        lo[j] = (_Float16)(wv - (float)wh);
                    }
                    Bpk[(size_t)(((l * 4 + c) * 2 + h) * 2 + 0) * 64 + t] = hi;
                    Bpk[(size_t)(((l * 4 + c) * 2 + h) * 2 + 1) * 64 + t] = lo;
                }
            }
        }
    } else {
        int i = (bx - NL) * 256 + t;
        if (i < NN * DD) xh[i] = __float2half(x[i]);
    }
}

// ---- shared gather body: agg[8] per lane, dims (lane&3)*8+i, replicated over streams ----
__device__ __forceinline__ void gather_body(const ushort* __restrict__ hin,
                                            const unsigned* __restrict__ epair,
                                            int p0, int p1, int lane, int st, int c4,
                                            float agg[8]) {
    const int4* hin4 = (const int4*)hin;
    for (int e0 = p0; e0 < p1; e0 += 32) {
        int m = p1 - e0;
        if (m > 32) m = 32;
        int s = 0;
        float v = 0.f;
        if (lane < m) {
            unsigned p = __builtin_nontemporal_load(epair + e0 + lane);
            s = (int)(p & 0x1FFFFu);
            v = __half2float(__ushort_as_half((unsigned short)(p >> 17)));
        }
        int nit = (m + 7) >> 3;
        #pragma unroll 2
        for (int j = 0; j < nit; ++j) {
            int sl = j * 8 + st;
            int   ss = __shfl(s, sl, 32);   // 0 (safe) when sl >= m
            float vv = __shfl(v, sl, 32);   // 0 when sl >= m
            int4 rw = hin4[(size_t)ss * 4 + c4];
            float2 f0 = __half22float2(*reinterpret_cast<__half2*>(&rw.x));
            float2 f1 = __half22float2(*reinterpret_cast<__half2*>(&rw.y));
            float2 f2 = __half22float2(*reinterpret_cast<__half2*>(&rw.z));
            float2 f3 = __half22float2(*reinterpret_cast<__half2*>(&rw.w));
            agg[0] = fmaf(vv, f0.x, agg[0]); agg[1] = fmaf(vv, f0.y, agg[1]);
            agg[2] = fmaf(vv, f1.x, agg[2]); agg[3] = fmaf(vv, f1.y, agg[3]);
            agg[4] = fmaf(vv, f2.x, agg[4]); agg[5] = fmaf(vv, f2.y, agg[5]);
            agg[6] = fmaf(vv, f3.x, agg[6]); agg[7] = fmaf(vv, f3.y, agg[7]);
        }
    }
    #pragma unroll
    for (int i = 0; i < 8; ++i) {
        agg[i] += __shfl_xor(agg[i], 4, 32);
        agg[i] += __shfl_xor(agg[i], 8, 32);
        agg[i] += __shfl_xor(agg[i], 16, 32);
    }
}

// --- pure hop: hout[n] = sum norm*hin[src], fp16 in/out ---
__global__ __launch_bounds__(256) void gather_kernel(
    const ushort* __restrict__ hin, ushort* __restrict__ hout,
    const int* __restrict__ ptr, const unsigned* __restrict__ epair) {
    int tid = threadIdx.x;
    int lane = tid & 31;
    int st = lane >> 2, c4 = lane & 3;
    int n = blockIdx.x * 8 + (tid >> 5);
    if (n >= NN) return;
    int p0 = ptr[n], p1 = ptr[n + 1];
    float agg[8] = {0.f, 0.f, 0.f, 0.f, 0.f, 0.f, 0.f, 0.f};
    gather_body(hin, epair, p0, p1, lane, st, c4, agg);
    if (lane < 4) {
        __half2 ha = __floats2half2_rn(agg[0], agg[1]);
        __half2 hb = __floats2half2_rn(agg[2], agg[3]);
        __half2 hc = __floats2half2_rn(agg[4], agg[5]);
        __half2 hd = __floats2half2_rn(agg[6], agg[7]);
        int4 pkv;
        pkv.x = *(int*)&ha; pkv.y = *(int*)&hb;
        pkv.z = *(int*)&hc; pkv.w = *(int*)&hd;
        ((int4*)hout)[(size_t)n * 4 + lane] = pkv;
    }
}

// --- fused k=3 gather + MFMA epilogue. 512 threads = 16 nodes; wave 0 prefetches its
//     A-fragments before the gather so those loads hide under gather latency. ---
__global__ __launch_bounds__(512) void k3ep_kernel(
    const ushort* __restrict__ f0, const ushort* __restrict__ h1,
    const ushort* __restrict__ h2,
    ushort* __restrict__ f0out, float* __restrict__ outf,
    const int* __restrict__ ptr, const unsigned* __restrict__ epair,
    const half8* __restrict__ Bp, const float* __restrict__ bias, int last) {
    __shared__ __half ldsH[16 * DD];
    int tid = threadIdx.x;
    int lane = tid & 31;
    int st = lane >> 2, c4 = lane & 3;
    int nloc = tid >> 5;                 // 0..15
    int n0 = blockIdx.x * 16;
    int n = n0 + nloc;                   // NN = 6250*16 exactly
    // wave-0 prefetch of A fragments (coalesced own-tile rows)
    half8 pA0, pA1, pA2;
    if (tid < 64) {
        int m = tid & 15, kq = tid >> 4;
        int ai = (n0 + m) * 4 + kq;
        pA0 = ((const half8*)f0)[ai];
        pA1 = ((const half8*)h1)[ai];
        pA2 = ((const half8*)h2)[ai];
    }
    int p0 = ptr[n], p1 = ptr[n + 1];
    float agg[8] = {0.f, 0.f, 0.f, 0.f, 0.f, 0.f, 0.f, 0.f};
    gather_body(h2, epair, p0, p1, lane, st, c4, agg);
    if (lane < 4) {
        __half2 ha = __floats2half2_rn(agg[0], agg[1]);
        __half2 hb = __floats2half2_rn(agg[2], agg[3]);
        __half2 hc = __floats2half2_rn(agg[4], agg[5]);
        __half2 hd = __floats2half2_rn(agg[6], agg[7]);
        int4 pkv;
        pkv.x = *(int*)&ha; pkv.y = *(int*)&hb;
        pkv.z = *(int*)&hc; pkv.w = *(int*)&hd;
        *(int4*)&ldsH[nloc * DD + c4 * 8] = pkv;
    }
    __syncthreads();
    if (tid < 64) {
        int m = tid & 15, kq = tid >> 4;
        f32x4 acc0 = {0.f, 0.f, 0.f, 0.f};
        f32x4 acc1 = {0.f, 0.f, 0.f, 0.f};
        acc0 = __builtin_amdgcn_mfma_f32_16x16x32_f16(pA0, Bp[0 * 64 + tid], acc0, 0, 0, 0);
        acc0 = __builtin_amdgcn_mfma_f32_16x16x32_f16(pA0, Bp[1 * 64 + tid], acc0, 0, 0, 0);
        acc1 = __builtin_amdgcn_mfma_f32_16x16x32_f16(pA0, Bp[2 * 64 + tid], acc1, 0, 0, 0);
        acc1 = __builtin_amdgcn_mfma_f32_16x16x32_f16(pA0, Bp[3 * 64 + tid], acc1, 0, 0, 0);
        acc0 = __builtin_amdgcn_mfma_f32_16x16x32_f16(pA1, Bp[4 * 64 + tid], acc0, 0, 0, 0);
        acc0 = __builtin_amdgcn_mfma_f32_16x16x32_f16(pA1, Bp[5 * 64 + tid], acc0, 0, 0, 0);
        acc1 = __builtin_amdgcn_mfma_f32_16x16x32_f16(pA1, Bp[6 * 64 + tid], acc1, 0, 0, 0);
        acc1 = __builtin_amdgcn_mfma_f32_16x16x32_f16(pA1, Bp[7 * 64 + tid], acc1, 0, 0, 0);
        acc0 = __builtin_amdgcn_mfma_f32_16x16x32_f16(pA2, Bp[8 * 64 + tid], acc0, 0, 0, 0);
        acc0 = __builtin_amdgcn_mfma_f32_16x16x32_f16(pA2, Bp[9 * 64 + tid], acc0, 0, 0, 0);
        acc1 = __builtin_amdgcn_mfma_f32_16x16x32_f16(pA2, Bp[10 * 64 + tid], acc1, 0, 0, 0);
        acc1 = __builtin_amdgcn_mfma_f32_16x16x32_f16(pA2, Bp[11 * 64 + tid], acc1, 0, 0, 0);
        half8 a3 = *(const half8*)&ldsH[m * DD + kq * 8];
        acc0 = __builtin_amdgcn_mfma_f32_16x16x32_f16(a3, Bp[12 * 64 + tid], acc0, 0, 0, 0);
        acc0 = __builtin_amdgcn_mfma_f32_16x16x32_f16(a3, Bp[13 * 64 + tid], acc0, 0, 0, 0);
        acc1 = __builtin_amdgcn_mfma_f32_16x16x32_f16(a3, Bp[14 * 64 + tid], acc1, 0, 0, 0);
        acc1 = __builtin_amdgcn_mfma_f32_16x16x32_f16(a3, Bp[15 * 64 + tid], acc1, 0, 0, 0);
        float b0 = bias[m], b1 = bias[16 + m];
        #pragma unroll
        for (int r = 0; r < 4; ++r) {
            int rowi = n0 + kq * 4 + r;
            float v0 = fmaxf(acc0[r] + b0, 0.f);
            float v1 = fmaxf(acc1[r] + b1, 0.f);
            if (last) {
                outf[rowi * DD + m] = v0;
                outf[rowi * DD + 16 + m] = v1;
            } else {
                ((__half*)f0out)[rowi * DD + m] = __float2half(v0);
                ((__half*)f0out)[rowi * DD + 16 + m] = __float2half(v1);
            }
        }
    }
}

extern "C" void kernel_launch(void* const* d_in, const int* in_sizes, int n_in,
                              void* d_out, int out_size, void* d_ws, size_t ws_size,
                              hipStream_t stream) {
    const float* x  = (const float*)d_in[0];
    const int*   ei = (const int*)d_in[1];
    const float* ew = (const float*)d_in[2];
    const float* W  = (const float*)d_in[3];
    const float* b  = (const float*)d_in[4];
    float* out = (float*)d_out;

    const int* row = ei;        // source
    const int* col = ei + NE;   // target

    // ws layout (bytes), ~34.5 MB:
    // pk 0.8M | epair 6.4M | h1 6.4M | h2 6.4M | f0 6.4M | rank 6.4M |
    // ptr 400016 | dis 400000 | pc 800000 | bsum 2048 | Bpk 49152
    char* base = (char*)d_ws;
    unsigned long long* pk = (unsigned long long*)base;
    unsigned* epair = (unsigned*)(base + 800000);
    ushort*   h1    = (ushort*)(base + 7200000);
    ushort*   h2    = (ushort*)(base + 13600000);
    ushort*   f0    = (ushort*)(base + 20000000);
    int*      rank  = (int*)(base + 26400000);
    int*      ptr   = (int*)(base + 32800000);
    float*    dis   = (float*)(base + 33200016);
    int2*     pc    = (int2*)(base + 33600016);
    int*      bsum  = (int*)(base + 34400016);
    half8*    Bpk   = (half8*)(base + 34402080);

    // ---- build CSR-by-target + norms ----
    hipMemsetAsync(pk, 0, NN * sizeof(unsigned long long), stream);
    cvtprep_kernel<<<NL + (NN * DD + 255) / 256, 256, 0, stream>>>(x, (__half*)f0, W, Bpk);
    hist_rank_kernel<<<(NE + 255) / 256, 256, 0, stream>>>(col, ew, pk, rank);
    scan_block_kernel<<<NB, 256, 0, stream>>>(pk, dis, ptr, bsum);
    scan_add_kernel<<<NB, 256, 0, stream>>>(ptr, bsum, dis, pc);
    fill_kernel<<<(NE + 255) / 256, 256, 0, stream>>>(row, col, ew, rank, dis, pc, epair);

    // ---- layers: f0 = layer input (fp16, updated in place by fused epilogue) ----
    const int grid = NN / 8;
    for (int l = 0; l < NL; ++l) {
        int lastl = (l == NL - 1);
        gather_kernel<<<grid, 256, 0, stream>>>(f0, h1, ptr, epair);   // k=1
        gather_kernel<<<grid, 256, 0, stream>>>(h1, h2, ptr, epair);   // k=2
        k3ep_kernel<<<NTB, 512, 0, stream>>>(f0, h1, h2, f0, out, ptr, epair,
                                             Bpk + (size_t)l * 1024,
                                             b + (size_t)l * DD, lastl);
    }
}

// Round 11
// 439.925 us; speedup vs baseline: 1.0367x; 1.0367x over previous
//
#include <hip/hip_runtime.h>
#include <hip/hip_fp16.h>

#define NN 100000
#define NE 1600000
#define DD 32
#define NL 3
#define NK 3
#define NB ((NN + 255) / 256)   // 391 scan blocks
#define NTB (NN / 16)           // 6250 fused-kernel blocks

typedef _Float16 half8 __attribute__((ext_vector_type(8)));
typedef float f32x4 __attribute__((ext_vector_type(4)));

// --- packed histogram, single copy: count [48..], fp(2^-40) wsum [0..48).
//     Returned old count = this edge's rank within its target's list. ---
__global__ void hist_rank_kernel(const int* __restrict__ col, const float* __restrict__ w,
                                 unsigned long long* __restrict__ pk, int* __restrict__ rank) {
    int e = blockIdx.x * blockDim.x + threadIdx.x;
    if (e < NE) {
        int c = col[e];
        unsigned long long enc = (1ull << 48) |
            (unsigned long long)((double)w[e] * 1099511627776.0);  // w * 2^40
        unsigned long long old = atomicAdd(&pk[c], enc);
        rank[e] = (int)(old >> 48);
    }
}

// --- per-block scan of counts (from pk) -> ptr partial + bsum; also dis ---
__global__ void scan_block_kernel(const unsigned long long* __restrict__ pk,
                                  float* __restrict__ dis,
                                  int* __restrict__ ptr, int* __restrict__ bsum) {
    __shared__ int s[256];
    int t = threadIdx.x;
    int i = blockIdx.x * 256 + t;
    unsigned long long p = (i < NN) ? pk[i] : 0ull;
    int v = (int)(p >> 48);
    s[t] = v;
    __syncthreads();
    for (int off = 1; off < 256; off <<= 1) {
        int add = (t >= off) ? s[t - off] : 0;
        __syncthreads();
        s[t] += add;
        __syncthreads();
    }
    if (i < NN) {
        ptr[i] = s[t] - v;
        float deg = (float)((double)(p & 0xFFFFFFFFFFFFull) * (1.0 / 1099511627776.0));
        dis[i] = deg > 0.f ? rsqrtf(deg) : 0.f;
    }
    if (t == 255) bsum[blockIdx.x] = s[255];
}

__global__ void scan_top_kernel(int* __restrict__ bsum, int* __restrict__ ptr) {
    __shared__ int s[512];
    int t = threadIdx.x;
    int v = (t < NB) ? bsum[t] : 0;
    s[t] = v;
    __syncthreads();
    for (int off = 1; off < 512; off <<= 1) {
        int add = (t >= off) ? s[t - off] : 0;
        __syncthreads();
        s[t] += add;
        __syncthreads();
    }
    if (t < NB) bsum[t] = s[t] - v;
    if (t == 0) ptr[NN] = NE;
}

// --- add block offsets; emit packed (ptr, dis) for fill's single random read ---
__global__ void scan_add_kernel(int* __restrict__ ptr, const int* __restrict__ bsum,
                                const float* __restrict__ dis, int2* __restrict__ pc) {
    int i = blockIdx.x * 256 + threadIdx.x;
    if (i < NN) {
        int pf = ptr[i] + bsum[i >> 8];
        ptr[i] = pf;
        pc[i] = make_int2(pf, __float_as_int(dis[i]));
    }
}

// --- fill CSR (no atomics): epair = (fp16_bits(norm) << 17) | src ---
__global__ void fill_kernel(const int* __restrict__ row, const int* __restrict__ col,
                            const float* __restrict__ w, const int* __restrict__ rank,
                            const float* __restrict__ dis, const int2* __restrict__ pc,
                            unsigned* __restrict__ epair) {
    int e = blockIdx.x * blockDim.x + threadIdx.x;
    if (e < NE) {
        int r = row[e], c = col[e];
        int2 P = pc[c];
        float nv = dis[r] * w[e] * __int_as_float(P.y);
        unsigned hb = (unsigned)__half_as_ushort(__float2half(nv));
        epair[P.x + rank[e]] = (hb << 17) | (unsigned)r;
    }
}

__global__ void cvt_kernel(const float* __restrict__ x, __half* __restrict__ xh) {
    int i = blockIdx.x * blockDim.x + threadIdx.x;
    if (i < NN * DD) xh[i] = __float2half(x[i]);
}

// --- pre-pack B fragments (hi/lo fp16 split, lane layout) for all layers ---
__global__ void prep_kernel(const float* __restrict__ W, half8* __restrict__ Bpk) {
    int l = blockIdx.x;
    int t = threadIdx.x;           // lane 0..63
    int m = t & 15, kq = t >> 4;
    for (int c = 0; c < 4; ++c) {
        for (int h = 0; h < 2; ++h) {
            half8 hi, lo;
            for (int j = 0; j < 8; ++j) {
                float w = W[(size_t)((l * 4 + c) * DD + kq * 8 + j) * DD + h * 16 + m];
                _Float16 wh = (_Float16)w;
                hi[j] = wh;
                lo[j] = (_Float16)(w - (float)wh);
            }
            Bpk[(size_t)(((l * 4 + c) * 2 + h) * 2 + 0) * 64 + t] = hi;
            Bpk[(size_t)(((l * 4 + c) * 2 + h) * 2 + 1) * 64 + t] = lo;
        }
    }
}

// ---- shared gather body: agg[8] per lane, dims (lane&3)*8+i, replicated over streams ----
__device__ __forceinline__ void gather_body(const ushort* __restrict__ hin,
                                            const unsigned* __restrict__ epair,
                                            int p0, int p1, int lane, int st, int c4,
                                            float agg[8]) {
    const int4* hin4 = (const int4*)hin;
    for (int e0 = p0; e0 < p1; e0 += 32) {
        int m = p1 - e0;
        if (m > 32) m = 32;
        int s = 0;
        float v = 0.f;
        if (lane < m) {
            unsigned p = __builtin_nontemporal_load(epair + e0 + lane);
            s = (int)(p & 0x1FFFFu);
            v = __half2float(__ushort_as_half((unsigned short)(p >> 17)));
        }
        int nit = (m + 7) >> 3;
        #pragma unroll 2
        for (int j = 0; j < nit; ++j) {
            int sl = j * 8 + st;
            int   ss = __shfl(s, sl, 32);   // 0 (safe) when sl >= m
            float vv = __shfl(v, sl, 32);   // 0 when sl >= m
            int4 rw = hin4[(size_t)ss * 4 + c4];
            float2 f0 = __half22float2(*reinterpret_cast<__half2*>(&rw.x));
            float2 f1 = __half22float2(*reinterpret_cast<__half2*>(&rw.y));
            float2 f2 = __half22float2(*reinterpret_cast<__half2*>(&rw.z));
            float2 f3 = __half22float2(*reinterpret_cast<__half2*>(&rw.w));
            agg[0] = fmaf(vv, f0.x, agg[0]); agg[1] = fmaf(vv, f0.y, agg[1]);
            agg[2] = fmaf(vv, f1.x, agg[2]); agg[3] = fmaf(vv, f1.y, agg[3]);
            agg[4] = fmaf(vv, f2.x, agg[4]); agg[5] = fmaf(vv, f2.y, agg[5]);
            agg[6] = fmaf(vv, f3.x, agg[6]); agg[7] = fmaf(vv, f3.y, agg[7]);
        }
    }
    #pragma unroll
    for (int i = 0; i < 8; ++i) {
        agg[i] += __shfl_xor(agg[i], 4, 32);
        agg[i] += __shfl_xor(agg[i], 8, 32);
        agg[i] += __shfl_xor(agg[i], 16, 32);
    }
}

// --- pure hop: hout[n] = sum norm*hin[src], fp16 in/out ---
__global__ __launch_bounds__(256) void gather_kernel(
    const ushort* __restrict__ hin, ushort* __restrict__ hout,
    const int* __restrict__ ptr, const unsigned* __restrict__ epair) {
    int tid = threadIdx.x;
    int lane = tid & 31;
    int st = lane >> 2, c4 = lane & 3;
    int n = blockIdx.x * 8 + (tid >> 5);
    if (n >= NN) return;
    int p0 = ptr[n], p1 = ptr[n + 1];
    float agg[8] = {0.f, 0.f, 0.f, 0.f, 0.f, 0.f, 0.f, 0.f};
    gather_body(hin, epair, p0, p1, lane, st, c4, agg);
    if (lane < 4) {
        __half2 ha = __floats2half2_rn(agg[0], agg[1]);
        __half2 hb = __floats2half2_rn(agg[2], agg[3]);
        __half2 hc = __floats2half2_rn(agg[4], agg[5]);
        __half2 hd = __floats2half2_rn(agg[6], agg[7]);
        int4 pkv;
        pkv.x = *(int*)&ha; pkv.y = *(int*)&hb;
        pkv.z = *(int*)&hc; pkv.w = *(int*)&hd;
        ((int4*)hout)[(size_t)n * 4 + lane] = pkv;
    }
}

// --- fused k=3 gather + MFMA epilogue. 512 threads = 16 nodes (gather, 32 lanes/node);
//     agg -> 1KB LDS tile -> wave 0 does o = b + [f0|h1|h2|h3]@W, relu, store.
//     h3 never hits global. In-place f0 update is safe: gather input is h2 only. ---
__global__ __launch_bounds__(512) void k3ep_kernel(
    const ushort* __restrict__ f0, const ushort* __restrict__ h1,
    const ushort* __restrict__ h2,
    ushort* __restrict__ f0out, float* __restrict__ outf,
    const int* __restrict__ ptr, const unsigned* __restrict__ epair,
    const half8* __restrict__ Bp, const float* __restrict__ bias, int last) {
    __shared__ __half ldsH[16 * DD];
    int tid = threadIdx.x;
    int lane = tid & 31;
    int st = lane >> 2, c4 = lane & 3;
    int nloc = tid >> 5;                 // 0..15
    int n0 = blockIdx.x * 16;
    int n = n0 + nloc;                   // NN = 6250*16 exactly, no guard needed
    int p0 = ptr[n], p1 = ptr[n + 1];
    float agg[8] = {0.f, 0.f, 0.f, 0.f, 0.f, 0.f, 0.f, 0.f};
    gather_body(h2, epair, p0, p1, lane, st, c4, agg);
    if (lane < 4) {
        __half2 ha = __floats2half2_rn(agg[0], agg[1]);
        __half2 hb = __floats2half2_rn(agg[2], agg[3]);
        __half2 hc = __floats2half2_rn(agg[4], agg[5]);
        __half2 hd = __floats2half2_rn(agg[6], agg[7]);
        int4 pkv;
        pkv.x = *(int*)&ha; pkv.y = *(int*)&hb;
        pkv.z = *(int*)&hc; pkv.w = *(int*)&hd;
        *(int4*)&ldsH[nloc * DD + c4 * 8] = pkv;
    }
    __syncthreads();
    if (tid < 64) {
        int m = tid & 15, kq = tid >> 4;
        int ai = (n0 + m) * 4 + kq;
        const half8* A0 = (const half8*)f0;
        const half8* A1 = (const half8*)h1;
        const half8* A2 = (const half8*)h2;
        f32x4 acc0 = {0.f, 0.f, 0.f, 0.f};
        f32x4 acc1 = {0.f, 0.f, 0.f, 0.f};
        half8 a;
        a = A0[ai];
        acc0 = __builtin_amdgcn_mfma_f32_16x16x32_f16(a, Bp[0 * 64 + tid], acc0, 0, 0, 0);
        acc0 = __builtin_amdgcn_mfma_f32_16x16x32_f16(a, Bp[1 * 64 + tid], acc0, 0, 0, 0);
        acc1 = __builtin_amdgcn_mfma_f32_16x16x32_f16(a, Bp[2 * 64 + tid], acc1, 0, 0, 0);
        acc1 = __builtin_amdgcn_mfma_f32_16x16x32_f16(a, Bp[3 * 64 + tid], acc1, 0, 0, 0);
        a = A1[ai];
        acc0 = __builtin_amdgcn_mfma_f32_16x16x32_f16(a, Bp[4 * 64 + tid], acc0, 0, 0, 0);
        acc0 = __builtin_amdgcn_mfma_f32_16x16x32_f16(a, Bp[5 * 64 + tid], acc0, 0, 0, 0);
        acc1 = __builtin_amdgcn_mfma_f32_16x16x32_f16(a, Bp[6 * 64 + tid], acc1, 0, 0, 0);
        acc1 = __builtin_amdgcn_mfma_f32_16x16x32_f16(a, Bp[7 * 64 + tid], acc1, 0, 0, 0);
        a = A2[ai];
        acc0 = __builtin_amdgcn_mfma_f32_16x16x32_f16(a, Bp[8 * 64 + tid], acc0, 0, 0, 0);
        acc0 = __builtin_amdgcn_mfma_f32_16x16x32_f16(a, Bp[9 * 64 + tid], acc0, 0, 0, 0);
        acc1 = __builtin_amdgcn_mfma_f32_16x16x32_f16(a, Bp[10 * 64 + tid], acc1, 0, 0, 0);
        acc1 = __builtin_amdgcn_mfma_f32_16x16x32_f16(a, Bp[11 * 64 + tid], acc1, 0, 0, 0);
        a = *(const half8*)&ldsH[m * DD + kq * 8];
        acc0 = __builtin_amdgcn_mfma_f32_16x16x32_f16(a, Bp[12 * 64 + tid], acc0, 0, 0, 0);
        acc0 = __builtin_amdgcn_mfma_f32_16x16x32_f16(a, Bp[13 * 64 + tid], acc0, 0, 0, 0);
        acc1 = __builtin_amdgcn_mfma_f32_16x16x32_f16(a, Bp[14 * 64 + tid], acc1, 0, 0, 0);
        acc1 = __builtin_amdgcn_mfma_f32_16x16x32_f16(a, Bp[15 * 64 + tid], acc1, 0, 0, 0);
        float b0 = bias[m], b1 = bias[16 + m];
        #pragma unroll
        for (int r = 0; r < 4; ++r) {
            int rowi = n0 + kq * 4 + r;
            float v0 = fmaxf(acc0[r] + b0, 0.f);
            float v1 = fmaxf(acc1[r] + b1, 0.f);
            if (last) {
                outf[rowi * DD + m] = v0;
                outf[rowi * DD + 16 + m] = v1;
            } else {
                ((__half*)f0out)[rowi * DD + m] = __float2half(v0);
                ((__half*)f0out)[rowi * DD + 16 + m] = __float2half(v1);
            }
        }
    }
}

extern "C" void kernel_launch(void* const* d_in, const int* in_sizes, int n_in,
                              void* d_out, int out_size, void* d_ws, size_t ws_size,
                              hipStream_t stream) {
    const float* x  = (const float*)d_in[0];
    const int*   ei = (const int*)d_in[1];
    const float* ew = (const float*)d_in[2];
    const float* W  = (const float*)d_in[3];
    const float* b  = (const float*)d_in[4];
    float* out = (float*)d_out;

    const int* row = ei;        // source
    const int* col = ei + NE;   // target

    // ws layout (bytes), ~34.5 MB:
    // pk 0.8M | epair 6.4M | h1 6.4M | h2 6.4M | f0 6.4M | rank 6.4M |
    // ptr 400016 | dis 400000 | pc 800000 | bsum 2048 | Bpk 49152
    char* base = (char*)d_ws;
    unsigned long long* pk = (unsigned long long*)base;
    unsigned* epair = (unsigned*)(base + 800000);
    ushort*   h1    = (ushort*)(base + 7200000);
    ushort*   h2    = (ushort*)(base + 13600000);
    ushort*   f0    = (ushort*)(base + 20000000);
    int*      rank  = (int*)(base + 26400000);
    int*      ptr   = (int*)(base + 32800000);
    float*    dis   = (float*)(base + 33200016);
    int2*     pc    = (int2*)(base + 33600016);
    int*      bsum  = (int*)(base + 34400016);
    half8*    Bpk   = (half8*)(base + 34402080);

    // ---- build CSR-by-target + norms ----
    hipMemsetAsync(pk, 0, NN * sizeof(unsigned long long), stream);
    cvt_kernel<<<(NN * DD + 255) / 256, 256, 0, stream>>>(x, (__half*)f0);
    hist_rank_kernel<<<(NE + 255) / 256, 256, 0, stream>>>(col, ew, pk, rank);
    scan_block_kernel<<<NB, 256, 0, stream>>>(pk, dis, ptr, bsum);
    scan_top_kernel<<<1, 512, 0, stream>>>(bsum, ptr);
    scan_add_kernel<<<NB, 256, 0, stream>>>(ptr, bsum, dis, pc);
    fill_kernel<<<(NE + 255) / 256, 256, 0, stream>>>(row, col, ew, rank, dis, pc, epair);
    prep_kernel<<<NL, 64, 0, stream>>>(W, Bpk);

    // ---- layers: f0 = layer input (fp16, updated in place by fused epilogue) ----
    const int grid = NN / 8;
    for (int l = 0; l < NL; ++l) {
        int lastl = (l == NL - 1);
        gather_kernel<<<grid, 256, 0, stream>>>(f0, h1, ptr, epair);   // k=1
        gather_kernel<<<grid, 256, 0, stream>>>(h1, h2, ptr, epair);   // k=2
        k3ep_kernel<<<NTB, 512, 0, stream>>>(f0, h1, h2, f0, out, ptr, epair,
                                             Bpk + (size_t)l * 1024,
                                             b + (size_t)l * DD, lastl);
    }
}